// Round 3
// baseline (343.143 us; speedup 1.0000x reference)
//
#include <hip/hip_runtime.h>

#define HOP   2
#define NFFT  7
#define WLEN  6
#define NFREQ 4

// cos(2*pi*m/7), sin(2*pi*m/7) for m = 0..6, compile-time constants.
__device__ __constant__ const float C7[7] = {
     1.0f,
     0.62348980185873359f,
    -0.22252093395631440f,
    -0.90096886790241915f,
    -0.90096886790241915f,
    -0.22252093395631440f,
     0.62348980185873359f
};
__device__ __constant__ const float S7[7] = {
     0.0f,
     0.78183148246802980f,
     0.97492791218182362f,
     0.43388373911755812f,
    -0.43388373911755812f,
    -0.97492791218182362f,
    -0.78183148246802980f
};

// One thread = one frame f of one batch row b.
// frame f uses x[b*L + 2f + n] * w[n], n = 0..5  (w_pad[6] == 0 dropped).
// PLANES layout: out[(b*4+k)*F + f] = re ; out[HALF + (b*4+k)*F + f] = im
__global__ __launch_bounds__(256) void stft_kernel(
    const float* __restrict__ x, const float* __restrict__ w,
    float* __restrict__ out,
    long long L, long long F, long long HALF, long long in0, long long outn)
{
    const long long f = (long long)blockIdx.x * blockDim.x + threadIdx.x;
    if (f >= F) return;
    const long long b = blockIdx.y;

    const long long xbase = b * L + 2 * f;
    if (xbase + (WLEN - 1) >= in0) return;   // never fault

    float wx[WLEN];
#pragma unroll
    for (int n = 0; n < WLEN; ++n) {
        wx[n] = x[xbase + n] * w[n];         // w reads wave-uniform -> s-cached
    }

#pragma unroll
    for (int k = 0; k < NFREQ; ++k) {
        float re = 0.f, im = 0.f;
#pragma unroll
        for (int n = 0; n < WLEN; ++n) {
            const int m = (k * n) % 7;       // compile-time under full unroll
            re = fmaf(wx[n],  C7[m], re);
            im = fmaf(wx[n], -S7[m], im);
        }
        const long long q = (b * NFREQ + k) * F + f;
        if (q < outn)        out[q] = re;            // re plane (coalesced)
        if (HALF + q < outn) out[HALF + q] = im;     // im plane (coalesced)
    }
}

extern "C" void kernel_launch(void* const* d_in, const int* in_sizes, int n_in,
                              void* d_out, int out_size, void* d_ws, size_t ws_size,
                              hipStream_t stream) {
    const float* x = (const float*)d_in[0];
    const float* w = (const float*)d_in[1];
    float* out = (float*)d_out;

    const long long B = 64;                         // fixed by the reference
    const long long L = (long long)in_sizes[0] / B; // 500000
    const long long F = 1 + (L - NFFT) / HOP;       // 249997
    const long long HALF = B * NFREQ * F;           // re-plane size

    dim3 block(256);
    dim3 grid((unsigned)((F + 255) / 256), (unsigned)B);
    stft_kernel<<<grid, block, 0, stream>>>(x, w, out, L, F, HALF,
                                            (long long)in_sizes[0],
                                            (long long)out_size);
}